// Round 2
// baseline (988.229 us; speedup 1.0000x reference)
//
#include <hip/hip_runtime.h>

// LinearFlexQMixer on MI355X — fused one-block-per-(batch,t) kernel, round 2.
//
// R1 failed at absmax 0.235. All GEMM/softmax phases re-verified against the
// reference; prime suspect is entity_mask dtype (bool may arrive as int32 per
// harness "integer -> const int*"). This round adds runtime mask-dtype
// detection (int32 0/1 data has all bytes at off%4!=0 == 0) and reads the
// mask through the detected view into an LDS copy.
//
// Restructured attention (16 queries only):
//   logits = (q_h @ Wk_h^T) @ x1^T      -- no K materialization
//   attn_h = (softmax(logits) @ x1) @ Wv_h  -- no V materialization

#define NA 16    // N_AGENTS
#define NEn 128  // NE
#define EDm 96   // ED
#define HEd 128  // HE
#define MDd 32   // MD
#define NHh 4    // NH
#define HDd 32   // HD = HE/NH

__device__ __forceinline__ float bf2f(unsigned short u) {
  return __uint_as_float(((unsigned)u) << 16);
}
__device__ __forceinline__ unsigned short f2bf(float f) {
  unsigned u = __float_as_uint(f);
  u += 0x7fffu + ((u >> 16) & 1u);  // round-to-nearest-even
  return (unsigned short)(u >> 16);
}

// Detect whether the mask buffer is int32 (0/1) or 1-byte bool.
// int32 0/1 little-endian => every byte at offset i%4!=0 is zero.
__global__ void mask_dtype_kernel(const unsigned char* __restrict__ m,
                                  int* __restrict__ flag) {
  __shared__ int any_nz;
  if (threadIdx.x == 0) any_nz = 0;
  __syncthreads();
  int local = 0;
  for (int i = threadIdx.x; i < 4096; i += 256) {
    if ((i & 3) != 0 && m[i] != 0) local = 1;
  }
  if (local) atomicOr(&any_nz, 1);
  __syncthreads();
  if (threadIdx.x == 0) *flag = (any_nz == 0) ? 1 : 0;  // 1 => int32
}

// LDS arena layout (bytes):
//   sx1 : bf16 [128][132]   0     .. 33792   (x1, row-padded)
//   sw  : f32  [16][128]    33792 .. 41984   (logits / softmax weights)
//   st  : f32  [16][128]    41984 .. 50176   (qW -> wx -> out, time-sliced)
//   sat : f32  [16][128]    50176 .. 58368   (attn accumulator)
//   sqh : f32  [16][32]     58368 .. 60416   (per-head q)
//   sres: f32  [32]         60416 .. 60544   (|w1| means, v partial sums)
#define SMEM_BYTES 60544

__global__ __launch_bounds__(256, 2) void qmix_kernel(
    const float* __restrict__ agent_qs, const float* __restrict__ entities,
    const unsigned char* __restrict__ emask_g, const int* __restrict__ mflag,
    const float* __restrict__ w_fc1w, const float* __restrict__ w_fc1b,
    const float* __restrict__ w_inw, const float* __restrict__ w_outw,
    const float* __restrict__ w_outb, const float* __restrict__ w_fc2w,
    const float* __restrict__ w_fc2b, const float* __restrict__ v_fc1w,
    const float* __restrict__ v_fc1b, const float* __restrict__ v_inw,
    const float* __restrict__ v_outw, const float* __restrict__ v_outb,
    const float* __restrict__ v_fc2w, const float* __restrict__ v_fc2b,
    float* __restrict__ out_g) {
  const int b = blockIdx.x;
  const int t = threadIdx.x;
  const float* ents = entities + (size_t)b * (NEn * EDm);

  __shared__ __align__(16) unsigned char smem_raw[SMEM_BYTES];
  __shared__ unsigned char sm[NEn];  // block's entity mask, dtype-normalized
  unsigned short* sx1 = (unsigned short*)smem_raw;          // [128][132] bf16
  float* sw  = (float*)(smem_raw + 33792);                  // [16][128]
  float* st  = (float*)(smem_raw + 41984);                  // [16][128]
  float* sat = (float*)(smem_raw + 50176);                  // [16][128]
  float* sqh = (float*)(smem_raw + 58368);                  // [16][32]
  float* sres = (float*)(smem_raw + 60416);                 // [32]

  // Load mask through detected dtype view.
  const int is_i32 = *mflag;
  if (t < NEn) {
    unsigned char mv;
    if (is_i32)
      mv = (unsigned char)(((const int*)emask_g)[(size_t)b * NEn + t] != 0);
    else
      mv = (unsigned char)(emask_g[(size_t)b * NEn + t] != 0);
    sm[t] = mv;
  }
  // all_e(mask) — each t<128 contributes its own just-written sm[t];
  // the intrinsic is also the barrier making sm visible to all.
  const int allE = __syncthreads_and((t < NEn) ? (int)sm[t] : 1);

  for (int p = 0; p < 2; ++p) {
    const float* fc1w = p ? v_fc1w : w_fc1w;
    const float* fc1b = p ? v_fc1b : w_fc1b;
    const float* inw  = p ? v_inw  : w_inw;
    const float* outw = p ? v_outw : w_outw;
    const float* outb = p ? v_outb : w_outb;
    const float* fc2w = p ? v_fc2w : w_fc2w;
    const float* fc2b = p ? v_fc2b : w_fc2b;

    // ---- Phase A: x1 = relu(ents @ fc1w + fc1b) -> sx1 bf16 ----
    {
      const int tx = t & 31, ty = t >> 5;
      const int j0 = tx * 4;
      const float4 bb = *(const float4*)(fc1b + j0);
      float acc[16][4];
#pragma unroll
      for (int i = 0; i < 16; ++i) {
        acc[i][0] = bb.x; acc[i][1] = bb.y; acc[i][2] = bb.z; acc[i][3] = bb.w;
      }
      for (int mm = 0; mm < EDm; mm += 4) {
        float Bv[4][4];
#pragma unroll
        for (int r = 0; r < 4; ++r) {
          const float4 tmp = *(const float4*)(fc1w + (mm + r) * HEd + j0);
          Bv[r][0] = tmp.x; Bv[r][1] = tmp.y; Bv[r][2] = tmp.z; Bv[r][3] = tmp.w;
        }
#pragma unroll
        for (int half = 0; half < 2; ++half) {
          float4 a4[8];
#pragma unroll
          for (int i = 0; i < 8; ++i)
            a4[i] = *(const float4*)(ents + (ty * 16 + half * 8 + i) * EDm + mm);
#pragma unroll
          for (int i = 0; i < 8; ++i) {
            const int ii = half * 8 + i;
            const float a0 = a4[i].x, a1 = a4[i].y, a2 = a4[i].z, a3 = a4[i].w;
#pragma unroll
            for (int j = 0; j < 4; ++j) {
              acc[ii][j] += a0 * Bv[0][j];
              acc[ii][j] += a1 * Bv[1][j];
              acc[ii][j] += a2 * Bv[2][j];
              acc[ii][j] += a3 * Bv[3][j];
            }
          }
        }
      }
#pragma unroll
      for (int i = 0; i < 16; ++i) {
        const int e = ty * 16 + i;
        ushort4 pk;
        pk.x = f2bf(fmaxf(acc[i][0], 0.f));
        pk.y = f2bf(fmaxf(acc[i][1], 0.f));
        pk.z = f2bf(fmaxf(acc[i][2], 0.f));
        pk.w = f2bf(fmaxf(acc[i][3], 0.f));
        *(ushort4*)(sx1 + e * 132 + j0) = pk;
      }
    }
    __syncthreads();

    for (int h = 0; h < NHh; ++h) {
      // ---- C0a: q_h[q][d] = sum_n x1[q][n] * inw[n][h*32+d]  (16x32, K=128)
      {
        const int d = t & 31;
        const int qb = (t >> 5) * 2;
        float a0 = 0.f, a1 = 0.f;
        const float* Wq = inw + h * HDd + d;
        for (int n = 0; n < HEd; n += 4) {
          const ushort4 xa = *(const ushort4*)(sx1 + qb * 132 + n);
          const ushort4 xb = *(const ushort4*)(sx1 + (qb + 1) * 132 + n);
          const float* wp = Wq + n * 384;
          const float w0 = wp[0], w1 = wp[384], w2 = wp[768], w3 = wp[1152];
          a0 += bf2f(xa.x) * w0; a0 += bf2f(xa.y) * w1;
          a0 += bf2f(xa.z) * w2; a0 += bf2f(xa.w) * w3;
          a1 += bf2f(xb.x) * w0; a1 += bf2f(xb.y) * w1;
          a1 += bf2f(xb.z) * w2; a1 += bf2f(xb.w) * w3;
        }
        sqh[qb * HDd + d] = a0;
        sqh[(qb + 1) * HDd + d] = a1;
      }
      __syncthreads();

      // ---- C0b: qW[q][m] = sum_d q_h[q][d] * inw[m][128+h*32+d]  (16x128, K=32)
      {
        const int m = t & 127;
        const int qg = (t >> 7) * 8;
        float acc[8] = {0.f, 0.f, 0.f, 0.f, 0.f, 0.f, 0.f, 0.f};
        const float* Wk = inw + m * 384 + HEd + h * HDd;
        for (int d = 0; d < HDd; d += 4) {
          const float4 wv = *(const float4*)(Wk + d);
#pragma unroll
          for (int i = 0; i < 8; ++i) {
            const float4 qv = *(const float4*)(sqh + (qg + i) * HDd + d);
            acc[i] += qv.x * wv.x; acc[i] += qv.y * wv.y;
            acc[i] += qv.z * wv.z; acc[i] += qv.w * wv.w;
          }
        }
#pragma unroll
        for (int i = 0; i < 8; ++i) st[(qg + i) * HEd + m] = acc[i];
      }
      __syncthreads();

      // ---- C2: logits[q][e] = sum_m qW[q][m] * x1[e][m], mask, scale ----
      {
        const int e = t & 127;
        const int qg = (t >> 7) * 8;
        float acc[8] = {0.f, 0.f, 0.f, 0.f, 0.f, 0.f, 0.f, 0.f};
        for (int m = 0; m < HEd; m += 4) {
          const ushort4 xv = *(const ushort4*)(sx1 + e * 132 + m);
          const float x0 = bf2f(xv.x), x1v = bf2f(xv.y);
          const float x2 = bf2f(xv.z), x3v = bf2f(xv.w);
#pragma unroll
          for (int i = 0; i < 8; ++i) {
            const float4 qv = *(const float4*)(st + (qg + i) * HEd + m);
            acc[i] += x0 * qv.x; acc[i] += x1v * qv.y;
            acc[i] += x2 * qv.z; acc[i] += x3v * qv.w;
          }
        }
        const int eM = (int)sm[e];
#pragma unroll
        for (int i = 0; i < 8; ++i) {
          const int qi = qg + i;
          sw[qi * NEn + e] =
              (((int)sm[qi] | eM) != 0) ? -1000000000.0f
                                        : acc[i] * 0.17677669529663687f;
        }
      }
      __syncthreads();

      // ---- softmax rows (q = t>>4, 16 lanes x 8 e each) ----
      {
        const int q = t >> 4, sub = t & 15;
        float* row = sw + q * NEn + sub * 8;
        const float4 v0 = *(const float4*)(row);
        const float4 v1 = *(const float4*)(row + 4);
        float l[8] = {v0.x, v0.y, v0.z, v0.w, v1.x, v1.y, v1.z, v1.w};
        float mx = l[0];
#pragma unroll
        for (int i = 1; i < 8; ++i) mx = fmaxf(mx, l[i]);
#pragma unroll
        for (int k = 1; k < 16; k <<= 1) mx = fmaxf(mx, __shfl_xor(mx, k, 64));
        float s = 0.f;
        float ex[8];
#pragma unroll
        for (int i = 0; i < 8; ++i) { ex[i] = __expf(l[i] - mx); s += ex[i]; }
#pragma unroll
        for (int k = 1; k < 16; k <<= 1) s += __shfl_xor(s, k, 64);
        const float sc = (((int)sm[q] | allE) != 0) ? 0.f : (1.f / s);
        *(float4*)(row) = make_float4(ex[0] * sc, ex[1] * sc, ex[2] * sc, ex[3] * sc);
        *(float4*)(row + 4) = make_float4(ex[4] * sc, ex[5] * sc, ex[6] * sc, ex[7] * sc);
      }
      __syncthreads();

      // ---- C3: wx[q][m] = sum_e w[q][e] * x1[e][m]  (overwrites qW in st) ----
      {
        const int m = t & 127;
        const int qg = (t >> 7) * 8;
        float acc[8] = {0.f, 0.f, 0.f, 0.f, 0.f, 0.f, 0.f, 0.f};
        for (int e = 0; e < NEn; e += 4) {
          const float xs0 = bf2f(sx1[(e + 0) * 132 + m]);
          const float xs1 = bf2f(sx1[(e + 1) * 132 + m]);
          const float xs2 = bf2f(sx1[(e + 2) * 132 + m]);
          const float xs3 = bf2f(sx1[(e + 3) * 132 + m]);
#pragma unroll
          for (int i = 0; i < 8; ++i) {
            const float4 wv = *(const float4*)(sw + (qg + i) * NEn + e);
            acc[i] += xs0 * wv.x; acc[i] += xs1 * wv.y;
            acc[i] += xs2 * wv.z; acc[i] += xs3 * wv.w;
          }
        }
#pragma unroll
        for (int i = 0; i < 8; ++i) st[(qg + i) * HEd + m] = acc[i];
      }
      __syncthreads();

      // ---- C4: attn[q][h*32+d] = sum_m wx[q][m] * inw[m][256+h*32+d] ----
      {
        const int d = t & 31;
        const int qb = (t >> 5) * 2;
        float a0 = 0.f, a1 = 0.f;
        const float* Wv = inw + 2 * HEd + h * HDd + d;
        for (int m = 0; m < HEd; m += 4) {
          const float4 p0 = *(const float4*)(st + qb * HEd + m);
          const float4 p1 = *(const float4*)(st + (qb + 1) * HEd + m);
          const float* wp = Wv + m * 384;
          const float w0 = wp[0], w1 = wp[384], w2 = wp[768], w3 = wp[1152];
          a0 += p0.x * w0; a0 += p0.y * w1; a0 += p0.z * w2; a0 += p0.w * w3;
          a1 += p1.x * w0; a1 += p1.y * w1; a1 += p1.z * w2; a1 += p1.w * w3;
        }
        sat[qb * HEd + h * HDd + d] = a0;
        sat[(qb + 1) * HEd + h * HDd + d] = a1;
      }
      __syncthreads();
    }  // heads

    // ---- OUT: out[q][j] = sum_m attn[q][m]*outw[m][j] + outb[j] -> st ----
    {
      const int j = t & 127;
      const int qg = (t >> 7) * 8;
      const float bj = outb[j];
      float acc[8];
#pragma unroll
      for (int i = 0; i < 8; ++i) acc[i] = bj;
      for (int m = 0; m < HEd; m += 4) {
        const float* wp = outw + m * HEd + j;
        const float w0 = wp[0], w1 = wp[HEd], w2 = wp[2 * HEd], w3 = wp[3 * HEd];
#pragma unroll
        for (int i = 0; i < 8; ++i) {
          const float4 at = *(const float4*)(sat + (qg + i) * HEd + m);
          acc[i] += at.x * w0; acc[i] += at.y * w1;
          acc[i] += at.z * w2; acc[i] += at.w * w3;
        }
      }
#pragma unroll
      for (int i = 0; i < 8; ++i) st[(qg + i) * HEd + j] = acc[i];
    }
    __syncthreads();

    // ---- X3 + masked means: x3[q][c] = sum_m out[q][m]*fc2w[m][c] + fc2b[c]
    {
      const int c = t & 31;
      const int qb = (t >> 5) * 2;
      float a0 = fc2b[c], a1 = fc2b[c];
      for (int m = 0; m < HEd; m += 4) {
        const float4 o0 = *(const float4*)(st + qb * HEd + m);
        const float4 o1 = *(const float4*)(st + (qb + 1) * HEd + m);
        const float* wp = fc2w + m * MDd + c;
        const float w0 = wp[0], w1 = wp[MDd], w2 = wp[2 * MDd], w3 = wp[3 * MDd];
        a0 += o0.x * w0; a0 += o0.y * w1; a0 += o0.z * w2; a0 += o0.w * w3;
        a1 += o1.x * w0; a1 += o1.y * w1; a1 += o1.z * w2; a1 += o1.w * w3;
      }
      if (sm[qb]) a0 = 0.f;
      if (sm[qb + 1]) a1 = 0.f;
#pragma unroll
      for (int k = 1; k < 32; k <<= 1) {
        a0 += __shfl_xor(a0, k, 64);
        a1 += __shfl_xor(a1, k, 64);
      }
      if (c == 0) {
        if (p == 0) {  // w1: |mean over MD| per agent
          sres[qb] = fabsf(a0) * (1.f / 32.f);
          sres[qb + 1] = fabsf(a1) * (1.f / 32.f);
        } else {  // v: raw row sums, combined below
          sres[16 + qb] = a0;
          sres[16 + qb + 1] = a1;
        }
      }
    }
    __syncthreads();
  }  // p

  if (t == 0) {
    const float* qs = agent_qs + (size_t)b * NA;
    float tot = 0.f, vs = 0.f;
#pragma unroll
    for (int q = 0; q < NA; ++q) {
      tot += qs[q] * sres[q];
      vs += sres[16 + q];
    }
    out_g[b] = tot + vs * (1.f / 512.f);
  }
}

extern "C" void kernel_launch(void* const* d_in, const int* in_sizes, int n_in,
                              void* d_out, int out_size, void* d_ws,
                              size_t ws_size, hipStream_t stream) {
  (void)n_in; (void)out_size; (void)ws_size;
  const int nb = in_sizes[0] / NA;  // BS*T = 1600
  int* mflag = (int*)d_ws;
  hipLaunchKernelGGL(mask_dtype_kernel, dim3(1), dim3(256), 0, stream,
                     (const unsigned char*)d_in[2], mflag);
  hipLaunchKernelGGL(qmix_kernel, dim3(nb), dim3(256), 0, stream,
                     (const float*)d_in[0], (const float*)d_in[1],
                     (const unsigned char*)d_in[2], (const int*)mflag,
                     (const float*)d_in[3], (const float*)d_in[4],
                     (const float*)d_in[5], (const float*)d_in[6],
                     (const float*)d_in[7], (const float*)d_in[8],
                     (const float*)d_in[9], (const float*)d_in[10],
                     (const float*)d_in[11], (const float*)d_in[12],
                     (const float*)d_in[13], (const float*)d_in[14],
                     (const float*)d_in[15], (const float*)d_in[16],
                     (float*)d_out);
}

// Round 3
// 306.448 us; speedup vs baseline: 3.2248x; 3.2248x over previous
//
#include <hip/hip_runtime.h>

// LinearFlexQMixer MI355X — round 3: full MFMA rewrite.
// All GEMM phases on v_mfma_f32_16x16x32_bf16. Weights pre-swizzled to
// bf16 fragment-linear layout in d_ws (coalesced global B/A-frag loads).
// x1/Q/qW/w/VT/attn/out live in LDS bf16 [rows][136] (272B rows = bank floor).

#define NA 16
#define NEn 128
#define EDm 96
#define HEd 128
#define MDd 32
#define ST 136  // LDS row stride (shorts); 272B = 17*16B -> aligned b128

typedef __attribute__((ext_vector_type(8))) short bf16x8;
typedef __attribute__((ext_vector_type(4))) float f32x4;

#define MFMA(a, b, c) __builtin_amdgcn_mfma_f32_16x16x32_bf16((a), (b), (c), 0, 0, 0)

// d_ws layout (bf16 elems), per hypernet p at p*HYPE:
#define OFF_W1 0       // [nt8][kt3][64][8]  B-frags for Phase A (fc1w)
#define OFF_WQ 12288   // [nt8][kt4][64][8]  B-frags for Q (inw cols 0:128, pre-scaled)
#define OFF_WK 28672   // [h4][nt8][64][8]   B-frags for qW (Wk^T per head, K=32)
#define OFF_WV 45056   // [h4][mt2][kt4][64][8] A-frags for V^T (Wv^T per head)
#define OFF_WO 61440   // [nt8][kt4][64][8]  B-frags for OUT (outw)
#define OFF_W2 77824   // [nt2][kt4][64][8]  B-frags for X3 (fc2w)
#define HYPE 81920
#define WS_FLAG_OFF 327680  // int flag: mask dtype

__device__ __forceinline__ unsigned short f2bf(float f) {
  unsigned u = __float_as_uint(f);
  u += 0x7fffu + ((u >> 16) & 1u);  // RNE
  return (unsigned short)(u >> 16);
}

// Store one 16x16 C-tile column (4 f32, rows row0+0..3, col) as bf16 into
// LDS row-major [.. ][ST]. Pairs lanes (col, col^1) via shfl so every dword
// is written by exactly one lane.
__device__ __forceinline__ void ctile_store(unsigned short* dst, int row0,
                                            int col, f32x4 v) {
  unsigned short m0 = f2bf(v[0]), m1 = f2bf(v[1]), m2 = f2bf(v[2]),
                 m3 = f2bf(v[3]);
  unsigned x = (unsigned)m0 | ((unsigned)m1 << 16);
  unsigned y = (unsigned)m2 | ((unsigned)m3 << 16);
  unsigned ox = (unsigned)__shfl_xor((int)x, 1);
  unsigned oy = (unsigned)__shfl_xor((int)y, 1);
  unsigned w0, w1;
  int ra;
  if ((threadIdx.x & 1) == 0) {
    ra = 0;
    w0 = (x & 0xffffu) | (ox << 16);        // row0:   (my m0, partner m0)
    w1 = (x >> 16) | (ox & 0xffff0000u);    // row0+1: (my m1, partner m1)
  } else {
    ra = 2;
    w0 = (oy & 0xffffu) | (y << 16);        // row0+2: (partner m2, my m2)
    w1 = (oy >> 16) | (y & 0xffff0000u);    // row0+3: (partner m3, my m3)
  }
  *(unsigned*)(dst + (row0 + ra) * ST + (col & ~1)) = w0;
  *(unsigned*)(dst + (row0 + ra + 1) * ST + (col & ~1)) = w1;
}

// ---- mask dtype detection (int32 0/1 => bytes at off%4!=0 all zero) ----
__global__ void mask_dtype_kernel(const unsigned char* __restrict__ m,
                                  int* __restrict__ flag) {
  __shared__ int any_nz;
  if (threadIdx.x == 0) any_nz = 0;
  __syncthreads();
  int local = 0;
  for (int i = threadIdx.x; i < 4096; i += 256)
    if ((i & 3) != 0 && m[i] != 0) local = 1;
  if (local) atomicOr(&any_nz, 1);
  __syncthreads();
  if (threadIdx.x == 0) *flag = (any_nz == 0) ? 1 : 0;
}

// ---- weight preprocessing: fp32 -> bf16 fragment-linear ----
__global__ void prep_kernel(const float* __restrict__ w_fc1w,
                            const float* __restrict__ w_inw,
                            const float* __restrict__ w_outw,
                            const float* __restrict__ w_fc2w,
                            const float* __restrict__ v_fc1w,
                            const float* __restrict__ v_inw,
                            const float* __restrict__ v_outw,
                            const float* __restrict__ v_fc2w,
                            unsigned short* __restrict__ ws) {
  const int g = blockIdx.x * 256 + threadIdx.x;  // 0 .. 163839
  const int p = g / HYPE;
  const int off = g - p * HYPE;
  const float* fc1w = p ? v_fc1w : w_fc1w;
  const float* inw = p ? v_inw : w_inw;
  const float* outw = p ? v_outw : w_outw;
  const float* fc2w = p ? v_fc2w : w_fc2w;
  float val;
  if (off < OFF_WQ) {  // W1: B[k][n] = fc1w[k*128+n], K=96
    int idx = off - OFF_W1;
    int j = idx & 7, l = (idx >> 3) & 63, rest = idx >> 9;
    int kt = rest % 3, nt = rest / 3;
    val = fc1w[(kt * 32 + (l >> 4) * 8 + j) * 128 + nt * 16 + (l & 15)];
  } else if (off < OFF_WK) {  // Wq (scaled): B[k][n] = inw[k*384+n]*s
    int idx = off - OFF_WQ;
    int j = idx & 7, l = (idx >> 3) & 63, rest = idx >> 9;
    int kt = rest & 3, nt = rest >> 2;
    val = inw[(kt * 32 + (l >> 4) * 8 + j) * 384 + nt * 16 + (l & 15)] *
          0.17677669529663687f;
  } else if (off < OFF_WV) {  // Wk^T per head: B[d][m] = inw[m*384+128+h*32+d]
    int idx = off - OFF_WK;
    int j = idx & 7, l = (idx >> 3) & 63, rest = idx >> 9;
    int nt = rest & 7, h = rest >> 3;
    val = inw[(nt * 16 + (l & 15)) * 384 + 128 + h * 32 + (l >> 4) * 8 + j];
  } else if (off < OFF_WO) {  // Wv^T per head: A[d][m] = inw[m*384+256+h*32+d]
    int idx = off - OFF_WV;
    int j = idx & 7, l = (idx >> 3) & 63, rest = idx >> 9;
    int kt = rest & 3, mt = (rest >> 2) & 1, h = rest >> 3;
    val = inw[(kt * 32 + (l >> 4) * 8 + j) * 384 + 256 + h * 32 + mt * 16 +
              (l & 15)];
  } else if (off < OFF_W2) {  // Wo: B[k][n] = outw[k*128+n]
    int idx = off - OFF_WO;
    int j = idx & 7, l = (idx >> 3) & 63, rest = idx >> 9;
    int kt = rest & 3, nt = rest >> 2;
    val = outw[(kt * 32 + (l >> 4) * 8 + j) * 128 + nt * 16 + (l & 15)];
  } else {  // fc2: B[k][n] = fc2w[k*32+n], N=32
    int idx = off - OFF_W2;
    int j = idx & 7, l = (idx >> 3) & 63, rest = idx >> 9;
    int kt = rest & 3, nt = rest >> 2;
    val = fc2w[(kt * 32 + (l >> 4) * 8 + j) * 32 + nt * 16 + (l & 15)];
  }
  ws[g] = f2bf(val);
}

// LDS (bytes): sx1 [128][136]bf16 0..34816 | sQ/sout 34816..39168 |
// sqw 39168..43520 | sW 43520..47872 | sVT [32][136] 47872..56576 |
// sattn 56576..60928 | sred f2[64] 60928..61440 | sres f32[32] 61440..61568 |
// sm u8[128] 61568..61696
#define SMEM_BYTES 61696

__global__ __launch_bounds__(256, 2) void qmix_mfma(
    const float* __restrict__ agent_qs, const float* __restrict__ entities,
    const unsigned char* __restrict__ emask_g,
    const unsigned short* __restrict__ wsw, const int* __restrict__ mflag,
    const float* __restrict__ w_fc1b, const float* __restrict__ w_outb,
    const float* __restrict__ w_fc2b, const float* __restrict__ v_fc1b,
    const float* __restrict__ v_outb, const float* __restrict__ v_fc2b,
    float* __restrict__ out_g) {
  const int t = threadIdx.x;
  const int wv = t >> 6;       // wave 0..3
  const int ln = t & 63;       // lane
  const int lr = ln & 15;      // tile row (A.m) / col (B.n / C.col)
  const int lq = ln >> 4;      // k-group / C row-group
  const int b = blockIdx.x;
  const float* ents = entities + (size_t)b * (NEn * EDm);

  __shared__ __align__(16) unsigned char smem[SMEM_BYTES];
  unsigned short* sx1 = (unsigned short*)smem;
  unsigned short* sQ = sx1 + 17408;     // also sout after head loop
  unsigned short* sqw = sx1 + 19584;
  unsigned short* sW = sx1 + 21760;
  unsigned short* sVT = sx1 + 23936;
  unsigned short* sattn = sx1 + 28288;
  float2* sred = (float2*)(smem + 60928);
  float* sredf = (float*)(smem + 60928);
  float* sres = (float*)(smem + 61440);
  unsigned char* sm = smem + 61568;

  // ---- entity mask (dtype-normalized) ----
  const int is_i32 = *mflag;
  int mv = 1;
  if (t < NEn) {
    if (is_i32)
      mv = (((const int*)emask_g)[(size_t)b * NEn + t] != 0) ? 1 : 0;
    else
      mv = (emask_g[(size_t)b * NEn + t] != 0) ? 1 : 0;
    sm[t] = (unsigned char)mv;
  }
  const int allE = __syncthreads_and(mv);

  for (int p = 0; p < 2; ++p) {
    const unsigned short* wsb = wsw + (size_t)p * HYPE;
    const float* fc1b = p ? v_fc1b : w_fc1b;
    const float* outb = p ? v_outb : w_outb;
    const float* fc2b = p ? v_fc2b : w_fc2b;

    // ---- Phase A: x1 = relu(E @ W1 + b) -> sx1 bf16 [e][m] ----
    {
#pragma unroll
      for (int mi = 0; mi < 2; ++mi) {
        const int mt = wv * 2 + mi;
        bf16x8 af[3];
        const float* erow = ents + (mt * 16 + lr) * EDm + lq * 8;
#pragma unroll
        for (int kt = 0; kt < 3; ++kt) {
          float4 u = *(const float4*)(erow + kt * 32);
          float4 v = *(const float4*)(erow + kt * 32 + 4);
          bf16x8 a;
          a[0] = (short)f2bf(u.x); a[1] = (short)f2bf(u.y);
          a[2] = (short)f2bf(u.z); a[3] = (short)f2bf(u.w);
          a[4] = (short)f2bf(v.x); a[5] = (short)f2bf(v.y);
          a[6] = (short)f2bf(v.z); a[7] = (short)f2bf(v.w);
          af[kt] = a;
        }
        for (int nt = 0; nt < 8; ++nt) {
          f32x4 acc = {0.f, 0.f, 0.f, 0.f};
          const unsigned short* bp = wsb + OFF_W1 + (nt * 3) * 512 + ln * 8;
#pragma unroll
          for (int kt = 0; kt < 3; ++kt)
            acc = MFMA(af[kt], *(const bf16x8*)(bp + kt * 512), acc);
          const float bias = fc1b[nt * 16 + lr];
          f32x4 r;
          r[0] = fmaxf(acc[0] + bias, 0.f); r[1] = fmaxf(acc[1] + bias, 0.f);
          r[2] = fmaxf(acc[2] + bias, 0.f); r[3] = fmaxf(acc[3] + bias, 0.f);
          ctile_store(sx1, mt * 16 + lq * 4, nt * 16 + lr, r);
        }
      }
    }
    __syncthreads();

    // ---- Q = x1[0:16] @ Wq' (scaled) -> sQ [16][128] ----
    {
      bf16x8 aq[4];
#pragma unroll
      for (int kt = 0; kt < 4; ++kt)
        aq[kt] = *(const bf16x8*)(sx1 + lr * ST + kt * 32 + lq * 8);
#pragma unroll
      for (int ni = 0; ni < 2; ++ni) {
        const int nt = wv * 2 + ni;
        f32x4 acc = {0.f, 0.f, 0.f, 0.f};
        const unsigned short* bp = wsb + OFF_WQ + (nt * 4) * 512 + ln * 8;
#pragma unroll
        for (int kt = 0; kt < 4; ++kt)
          acc = MFMA(aq[kt], *(const bf16x8*)(bp + kt * 512), acc);
        ctile_store(sQ, lq * 4, nt * 16 + lr, acc);
      }
    }
    __syncthreads();

    for (int h = 0; h < 4; ++h) {
      // ---- merged: qW = Q_h @ Wk_h^T  and  V^T_h = Wv_h^T @ x1^T ----
      {
        bf16x8 aQ = *(const bf16x8*)(sQ + lr * ST + h * 32 + lq * 8);
#pragma unroll
        for (int ni = 0; ni < 2; ++ni) {
          const int nt = wv * 2 + ni;
          bf16x8 bk =
              *(const bf16x8*)(wsb + OFF_WK + (h * 8 + nt) * 512 + ln * 8);
          f32x4 acc = {0.f, 0.f, 0.f, 0.f};
          acc = MFMA(aQ, bk, acc);
          ctile_store(sqw, lq * 4, nt * 16 + lr, acc);
        }
        bf16x8 av[2][4];
#pragma unroll
        for (int mt = 0; mt < 2; ++mt)
#pragma unroll
          for (int kt = 0; kt < 4; ++kt)
            av[mt][kt] = *(const bf16x8*)(wsb + OFF_WV +
                                          (((h * 2 + mt) * 4) + kt) * 512 +
                                          ln * 8);
#pragma unroll
        for (int ni = 0; ni < 2; ++ni) {
          const int nt = wv * 2 + ni;
          bf16x8 bx[4];
#pragma unroll
          for (int kt = 0; kt < 4; ++kt)
            bx[kt] =
                *(const bf16x8*)(sx1 + (nt * 16 + lr) * ST + kt * 32 + lq * 8);
#pragma unroll
          for (int mt = 0; mt < 2; ++mt) {
            f32x4 acc = {0.f, 0.f, 0.f, 0.f};
#pragma unroll
            for (int kt = 0; kt < 4; ++kt) acc = MFMA(av[mt][kt], bx[kt], acc);
            ctile_store(sVT, mt * 16 + lq * 4, nt * 16 + lr, acc);
          }
        }
      }
      __syncthreads();

      // ---- logits = qW @ x1^T, mask cols, wave-local softmax stats ----
      float mx[4], ex0[4], ex1[4];
      {
        bf16x8 aw[4];
#pragma unroll
        for (int kt = 0; kt < 4; ++kt)
          aw[kt] = *(const bf16x8*)(sqw + lr * ST + kt * 32 + lq * 8);
        f32x4 a0 = {0.f, 0.f, 0.f, 0.f}, a1 = {0.f, 0.f, 0.f, 0.f};
        const int nt0 = wv * 2, nt1 = nt0 + 1;
#pragma unroll
        for (int kt = 0; kt < 4; ++kt) {
          bf16x8 b0 =
              *(const bf16x8*)(sx1 + (nt0 * 16 + lr) * ST + kt * 32 + lq * 8);
          bf16x8 b1 =
              *(const bf16x8*)(sx1 + (nt1 * 16 + lr) * ST + kt * 32 + lq * 8);
          a0 = MFMA(aw[kt], b0, a0);
          a1 = MFMA(aw[kt], b1, a1);
        }
        const int e0m = sm[nt0 * 16 + lr], e1m = sm[nt1 * 16 + lr];
        float l0[4], l1[4];
#pragma unroll
        for (int r = 0; r < 4; ++r) {
          l0[r] = e0m ? -1e9f : a0[r];
          l1[r] = e1m ? -1e9f : a1[r];
          mx[r] = fmaxf(l0[r], l1[r]);
        }
#pragma unroll
        for (int k = 1; k < 16; k <<= 1)
#pragma unroll
          for (int r = 0; r < 4; ++r)
            mx[r] = fmaxf(mx[r], __shfl_xor(mx[r], k));
        float sl[4];
#pragma unroll
        for (int r = 0; r < 4; ++r) {
          ex0[r] = __expf(l0[r] - mx[r]);
          ex1[r] = __expf(l1[r] - mx[r]);
          sl[r] = ex0[r] + ex1[r];
        }
#pragma unroll
        for (int k = 1; k < 16; k <<= 1)
#pragma unroll
          for (int r = 0; r < 4; ++r) sl[r] += __shfl_xor(sl[r], k);
        if (lr == 0) {
#pragma unroll
          for (int r = 0; r < 4; ++r)
            sred[wv * 16 + lq * 4 + r] = make_float2(mx[r], sl[r]);
        }
      }
      __syncthreads();

      // ---- softmax finish -> sW bf16 ----
      {
        f32x4 w0v, w1v;
#pragma unroll
        for (int r = 0; r < 4; ++r) {
          const int row = lq * 4 + r;
          float2 p0 = sred[row], p1 = sred[16 + row], p2 = sred[32 + row],
                 p3 = sred[48 + row];
          float M = fmaxf(fmaxf(p0.x, p1.x), fmaxf(p2.x, p3.x));
          float S = __expf(p0.x - M) * p0.y + __expf(p1.x - M) * p1.y +
                    __expf(p2.x - M) * p2.y + __expf(p3.x - M) * p3.y;
          const float sc = ((int)sm[row] | allE) ? 0.f : (1.f / S);
          const float f = __expf(mx[r] - M) * sc;
          w0v[r] = ex0[r] * f;
          w1v[r] = ex1[r] * f;
        }
        ctile_store(sW, lq * 4, wv * 32 + lr, w0v);
        ctile_store(sW, lq * 4, wv * 32 + 16 + lr, w1v);
      }
      __syncthreads();

      // ---- attn_h = w @ V_h -> sattn cols h*32.. (waves 0,1) ----
      if (wv < 2) {
        bf16x8 afr[4];
#pragma unroll
        for (int kt = 0; kt < 4; ++kt)
          afr[kt] = *(const bf16x8*)(sW + lr * ST + kt * 32 + lq * 8);
        f32x4 acc = {0.f, 0.f, 0.f, 0.f};
#pragma unroll
        for (int kt = 0; kt < 4; ++kt) {
          bf16x8 bfr =
              *(const bf16x8*)(sVT + (wv * 16 + lr) * ST + kt * 32 + lq * 8);
          acc = MFMA(afr[kt], bfr, acc);
        }
        ctile_store(sattn, lq * 4, h * 32 + wv * 16 + lr, acc);
      }
      __syncthreads();
    }  // heads

    // ---- OUT = attn @ Wo + bo -> sout (overlays sQ) ----
    {
      bf16x8 aa[4];
#pragma unroll
      for (int kt = 0; kt < 4; ++kt)
        aa[kt] = *(const bf16x8*)(sattn + lr * ST + kt * 32 + lq * 8);
#pragma unroll
      for (int ni = 0; ni < 2; ++ni) {
        const int nt = wv * 2 + ni;
        f32x4 acc = {0.f, 0.f, 0.f, 0.f};
        const unsigned short* bp = wsb + OFF_WO + (nt * 4) * 512 + ln * 8;
#pragma unroll
        for (int kt = 0; kt < 4; ++kt)
          acc = MFMA(aa[kt], *(const bf16x8*)(bp + kt * 512), acc);
        const float bj = outb[nt * 16 + lr];
        f32x4 r;
        r[0] = acc[0] + bj; r[1] = acc[1] + bj;
        r[2] = acc[2] + bj; r[3] = acc[3] + bj;
        ctile_store(sQ, lq * 4, nt * 16 + lr, r);  // sQ == sout
      }
    }
    __syncthreads();

    // ---- X3 = out @ fc2 + b, mask rows, row-sum (waves 0,1) ----
    if (wv < 2) {
      bf16x8 ao[4];
#pragma unroll
      for (int kt = 0; kt < 4; ++kt)
        ao[kt] = *(const bf16x8*)(sQ + lr * ST + kt * 32 + lq * 8);
      f32x4 acc = {0.f, 0.f, 0.f, 0.f};
      const unsigned short* bp = wsb + OFF_W2 + (wv * 4) * 512 + ln * 8;
#pragma unroll
      for (int kt = 0; kt < 4; ++kt)
        acc = MFMA(ao[kt], *(const bf16x8*)(bp + kt * 512), acc);
      const float bc = fc2b[wv * 16 + lr];
      float rs[4];
#pragma unroll
      for (int r = 0; r < 4; ++r) {
        const int row = lq * 4 + r;
        rs[r] = sm[row] ? 0.f : (acc[r] + bc);
      }
#pragma unroll
      for (int k = 1; k < 16; k <<= 1)
#pragma unroll
        for (int r = 0; r < 4; ++r) rs[r] += __shfl_xor(rs[r], k);
      if (lr == 0) {
#pragma unroll
        for (int r = 0; r < 4; ++r) sredf[wv * 16 + lq * 4 + r] = rs[r];
      }
    }
    __syncthreads();
    if (t < 16) {
      const float s = sredf[t] + sredf[16 + t];
      if (p == 0)
        sres[t] = fabsf(s) * (1.f / 32.f);
      else
        sres[16 + t] = s;
    }
    __syncthreads();
  }  // p

  if (t == 0) {
    const float* qs = agent_qs + (size_t)b * NA;
    float tot = 0.f, vs = 0.f;
#pragma unroll
    for (int q = 0; q < NA; ++q) {
      tot += qs[q] * sres[q];
      vs += sres[16 + q];
    }
    out_g[b] = tot + vs * (1.f / 512.f);
  }
}

extern "C" void kernel_launch(void* const* d_in, const int* in_sizes, int n_in,
                              void* d_out, int out_size, void* d_ws,
                              size_t ws_size, hipStream_t stream) {
  (void)n_in; (void)out_size; (void)ws_size;
  const int nb = in_sizes[0] / NA;  // BS*T = 1600
  unsigned short* wsw = (unsigned short*)d_ws;
  int* mflag = (int*)((char*)d_ws + WS_FLAG_OFF);

  hipLaunchKernelGGL(mask_dtype_kernel, dim3(1), dim3(256), 0, stream,
                     (const unsigned char*)d_in[2], mflag);
  hipLaunchKernelGGL(prep_kernel, dim3(2 * HYPE / 256), dim3(256), 0, stream,
                     (const float*)d_in[3], (const float*)d_in[5],
                     (const float*)d_in[6], (const float*)d_in[8],
                     (const float*)d_in[10], (const float*)d_in[12],
                     (const float*)d_in[13], (const float*)d_in[15], wsw);
  hipLaunchKernelGGL(qmix_mfma, dim3(nb), dim3(256), 0, stream,
                     (const float*)d_in[0], (const float*)d_in[1],
                     (const unsigned char*)d_in[2], (const unsigned short*)wsw,
                     (const int*)mflag, (const float*)d_in[4],
                     (const float*)d_in[7], (const float*)d_in[9],
                     (const float*)d_in[11], (const float*)d_in[14],
                     (const float*)d_in[16], (float*)d_out);
}